// Round 6
// baseline (1160.301 us; speedup 1.0000x reference)
//
#include <hip/hip_runtime.h>

#define N_USERS 100000
#define M_ITEMS 50000
#define NNODES  (N_USERS + M_ITEMS)
#define EMBED   64
#define N_LAYERS 3
#define BATCH   8192

#define NU_E ((size_t)N_USERS * EMBED)   // 6,400,000 floats
#define NI_E ((size_t)M_ITEMS * EMBED)   // 3,200,000 floats
#define NE   ((size_t)NNODES * EMBED)    // 9,600,000 floats

#define NPB    256                        // nodes per bucket
#define NBUCK  ((NNODES + NPB - 1) / NPB) // 586
#define PBLK   256                        // partition blocks
#define DBINS  1024                       // degree-sort bins
#define PRED_BLOCKS ((BATCH * 64) / 256)  // 2048

typedef unsigned int uint;

// bf16 helpers (RNE pack, cheap unpack)
static __device__ __forceinline__ ushort f2bf(float f) {
    uint u = __float_as_uint(f);
    return (ushort)((u + 0x7fffu + ((u >> 16) & 1u)) >> 16);
}
static __device__ __forceinline__ float bf_lo(uint u) { return __uint_as_float(u << 16); }
static __device__ __forceinline__ float bf_hi(uint u) { return __uint_as_float(u & 0xffff0000u); }

// ---------------------------------------------------------------------------
// sum = concat(eu0, ei0) fp32 ; Ua/Ia = bf16 copies.
// ---------------------------------------------------------------------------
__global__ void init_emb(const float* __restrict__ eu, const float* __restrict__ ei,
                         ushort* __restrict__ Ua, ushort* __restrict__ Ia,
                         float* __restrict__ sum) {
    size_t t = (size_t)blockIdx.x * blockDim.x + threadIdx.x;   // float4 index
    const size_t nu4 = NU_E / 4;
    const size_t n4  = NE / 4;
    if (t >= n4) return;
    float4 v;
    if (t < nu4) {
        v = ((const float4*)eu)[t];
        ((ushort4*)Ua)[t] = make_ushort4(f2bf(v.x), f2bf(v.y), f2bf(v.z), f2bf(v.w));
    } else {
        v = ((const float4*)ei)[t - nu4];
        ((ushort4*)Ia)[t - nu4] = make_ushort4(f2bf(v.x), f2bf(v.y), f2bf(v.z), f2bf(v.w));
    }
    ((float4*)sum)[t] = v;
}

// ---------------------------------------------------------------------------
// K1: per-block LDS histogram of coarse buckets (src >> 8) -> global Hg
// ---------------------------------------------------------------------------
__global__ void hist_bucket(const int* __restrict__ src, int* __restrict__ Hg,
                            int nnz, int tile) {
    __shared__ int h[NBUCK];
    for (int i = threadIdx.x; i < NBUCK; i += blockDim.x) h[i] = 0;
    __syncthreads();
    int base = blockIdx.x * tile;
    int end  = min(base + tile, nnz);
    for (int i = base + threadIdx.x; i < end; i += blockDim.x)
        atomicAdd(&h[src[i] >> 8], 1);
    __syncthreads();
    for (int i = threadIdx.x; i < NBUCK; i += blockDim.x)
        if (h[i]) atomicAdd(&Hg[i], h[i]);
}

// ---------------------------------------------------------------------------
// K2: exclusive scan of bucket totals -> bucket_base[NBUCK+1], bucketCursor
// ---------------------------------------------------------------------------
__global__ void scan_bucket(const int* __restrict__ Hg, int* __restrict__ bucket_base,
                            int* __restrict__ bucketCursor, int nnz) {
    __shared__ int lds[1024];
    int tid = threadIdx.x;
    int v = (tid < NBUCK) ? Hg[tid] : 0;
    lds[tid] = v;
    __syncthreads();
    for (int off = 1; off < 1024; off <<= 1) {
        int t = (tid >= off) ? lds[tid - off] : 0;
        __syncthreads();
        lds[tid] += t;
        __syncthreads();
    }
    if (tid < NBUCK) {
        int ex = (tid > 0) ? lds[tid - 1] : 0;
        bucket_base[tid]   = ex;
        bucketCursor[tid]  = ex;
    }
    if (tid == NBUCK) bucket_base[tid] = nnz;
}

// ---------------------------------------------------------------------------
// K3: partition edges into coarse buckets (LDS cursors, contiguous runs out).
// ebuf.x = (src & 255) | (dst_local << 8)
// ---------------------------------------------------------------------------
__global__ void partition_kernel(const int* __restrict__ src, const int* __restrict__ dst,
                                 const float* __restrict__ vals,
                                 int* __restrict__ bucketCursor, int2* __restrict__ ebuf,
                                 int nnz, int tile) {
    __shared__ int h[NBUCK];
    __shared__ int cur[NBUCK];
    for (int i = threadIdx.x; i < NBUCK; i += blockDim.x) h[i] = 0;
    __syncthreads();
    int base = blockIdx.x * tile;
    int end  = min(base + tile, nnz);
    for (int i = base + threadIdx.x; i < end; i += blockDim.x)
        atomicAdd(&h[src[i] >> 8], 1);
    __syncthreads();
    for (int i = threadIdx.x; i < NBUCK; i += blockDim.x)
        cur[i] = h[i] ? atomicAdd(&bucketCursor[i], h[i]) : 0;
    __syncthreads();
    for (int i = base + threadIdx.x; i < end; i += blockDim.x) {
        int s = src[i];
        int d = dst[i];
        float v = vals[i];
        if (d >= N_USERS) d -= N_USERS;          // bipartite-local dst index
        int p = atomicAdd(&cur[s >> 8], 1);
        ebuf[p] = make_int2((s & 255) | (d << 8), __float_as_int(v));
    }
}

// ---------------------------------------------------------------------------
// K4: one block per bucket: LDS counts+scan -> offs[], sort edges into ep.
// ---------------------------------------------------------------------------
__global__ void bucket_sort(const int* __restrict__ bucket_base, const int2* __restrict__ ebuf,
                            int* __restrict__ offs, int2* __restrict__ ep, int nnz) {
    __shared__ int cnt[256];
    __shared__ int sc[256];
    __shared__ int cur[256];
    int b   = blockIdx.x;
    int tid = threadIdx.x;
    int beg = bucket_base[b];
    int end = bucket_base[b + 1];
    if (tid < 256) cnt[tid] = 0;
    __syncthreads();
    for (int i = beg + tid; i < end; i += blockDim.x)
        atomicAdd(&cnt[ebuf[i].x & 255], 1);
    __syncthreads();
    if (tid < 256) sc[tid] = cnt[tid];
    __syncthreads();
    for (int off = 1; off < 256; off <<= 1) {
        int t = (tid >= off && tid < 256) ? sc[tid - off] : 0;
        __syncthreads();
        if (tid < 256) sc[tid] += t;
        __syncthreads();
    }
    if (tid < 256) {
        int nodeBase = beg + ((tid > 0) ? sc[tid - 1] : 0);
        int node = b * NPB + tid;
        if (node < NNODES) offs[node] = nodeBase;
        cur[tid] = nodeBase;
    }
    __syncthreads();
    for (int i = beg + tid; i < end; i += blockDim.x) {
        int2 e = ebuf[i];
        int p = atomicAdd(&cur[e.x & 255], 1);
        ep[p] = make_int2(e.x >> 8, e.y);
    }
    if (b == 0 && tid == 0) offs[NNODES] = nnz;
}

// ---------------------------------------------------------------------------
// Degree-sort: counting sort of nodes by degree -> perm[]
// ---------------------------------------------------------------------------
__global__ void deg_hist(const int* __restrict__ offs, int* __restrict__ dhist) {
    int n = blockIdx.x * blockDim.x + threadIdx.x;
    if (n >= NNODES) return;
    int d = offs[n + 1] - offs[n];
    atomicAdd(&dhist[min(d, DBINS - 1)], 1);
}

__global__ void deg_scan(const int* __restrict__ dhist, int* __restrict__ dcur) {
    __shared__ int lds[DBINS];
    int tid = threadIdx.x;
    lds[tid] = dhist[tid];
    __syncthreads();
    for (int off = 1; off < DBINS; off <<= 1) {
        int t = (tid >= off) ? lds[tid - off] : 0;
        __syncthreads();
        lds[tid] += t;
        __syncthreads();
    }
    dcur[tid] = (tid > 0) ? lds[tid - 1] : 0;   // exclusive
}

__global__ void deg_scatter(const int* __restrict__ offs, int* __restrict__ dcur,
                            int* __restrict__ perm) {
    int n = blockIdx.x * blockDim.x + threadIdx.x;
    if (n >= NNODES) return;
    int d = offs[n + 1] - offs[n];
    int pos = atomicAdd(&dcur[min(d, DBINS - 1)], 1);
    perm[pos] = n;
}

// ---------------------------------------------------------------------------
// Merged gather over ALL nodes in degree-sorted order.
// 8 nodes/wave, 8 lanes/node; node = perm[ln]; per-node src/dst buffers
// selected by bipartite side. Both sides read only OLD buffers (no race).
// ---------------------------------------------------------------------------
__global__ void gather_merged(const int* __restrict__ offs, const int2* __restrict__ ep,
                              const int* __restrict__ perm,
                              const ushort* __restrict__ Uold, const ushort* __restrict__ Iold,
                              ushort* __restrict__ Unew, ushort* __restrict__ Inew,
                              float* __restrict__ sum, int writeOut) {
    int t = blockIdx.x * blockDim.x + threadIdx.x;
    int wave = t >> 6;
    int lane = t & 63;
    int g = lane >> 3;              // node slot within wave
    int q = lane & 7;               // uint4 chunk within row
    int ln = wave * 8 + g;
    bool valid = ln < NNODES;
    int node = valid ? perm[ln] : 0;
    int start = valid ? offs[node] : 0;
    int deg   = valid ? offs[node + 1] - start : 0;
    bool isUser = node < N_USERS;
    const ushort* other = isUser ? Iold : Uold;

    // wave-uniform max degree (≈ deg thanks to degree sorting)
    int md = deg;
    #pragma unroll
    for (int off = 8; off <= 32; off <<= 1) md = max(md, __shfl_xor(md, off));

    float a0=0.f,a1=0.f,a2=0.f,a3=0.f,a4=0.f,a5=0.f,a6=0.f,a7=0.f;
    for (int k = 0; k < md; k += 2) {
        bool p0 = k < deg, p1 = k + 1 < deg;
        int2 e0 = p0 ? ep[start + k]     : make_int2(0, 0);
        int2 e1 = p1 ? ep[start + k + 1] : make_int2(0, 0);
        if (p0) {
            float v = __int_as_float(e0.y);
            uint4 r = ((const uint4*)other)[(size_t)e0.x * 8 + q];
            a0 = fmaf(v, bf_lo(r.x), a0);  a1 = fmaf(v, bf_hi(r.x), a1);
            a2 = fmaf(v, bf_lo(r.y), a2);  a3 = fmaf(v, bf_hi(r.y), a3);
            a4 = fmaf(v, bf_lo(r.z), a4);  a5 = fmaf(v, bf_hi(r.z), a5);
            a6 = fmaf(v, bf_lo(r.w), a6);  a7 = fmaf(v, bf_hi(r.w), a7);
        }
        if (p1) {
            float v = __int_as_float(e1.y);
            uint4 r = ((const uint4*)other)[(size_t)e1.x * 8 + q];
            a0 = fmaf(v, bf_lo(r.x), a0);  a1 = fmaf(v, bf_hi(r.x), a1);
            a2 = fmaf(v, bf_lo(r.y), a2);  a3 = fmaf(v, bf_hi(r.y), a3);
            a4 = fmaf(v, bf_lo(r.z), a4);  a5 = fmaf(v, bf_hi(r.z), a5);
            a6 = fmaf(v, bf_lo(r.w), a6);  a7 = fmaf(v, bf_hi(r.w), a7);
        }
    }

    if (!valid) return;
    if (writeOut) {
        uint4 o;
        o.x = (uint)f2bf(a0) | ((uint)f2bf(a1) << 16);
        o.y = (uint)f2bf(a2) | ((uint)f2bf(a3) << 16);
        o.z = (uint)f2bf(a4) | ((uint)f2bf(a5) << 16);
        o.w = (uint)f2bf(a6) | ((uint)f2bf(a7) << 16);
        int local = isUser ? node : node - N_USERS;
        ((uint4*)(isUser ? Unew : Inew))[(size_t)local * 8 + q] = o;
    }
    float4* sp = (float4*)(sum + (size_t)node * EMBED) + 2 * q;
    float4 s0 = sp[0], s1 = sp[1];
    s0.x += a0; s0.y += a1; s0.z += a2; s0.w += a3;
    s1.x += a4; s1.y += a5; s1.z += a6; s1.w += a7;
    sp[0] = s0; sp[1] = s1;
}

// ---------------------------------------------------------------------------
// One wave per batch element; reg-loss partials per block (NO global atomic).
// ---------------------------------------------------------------------------
__global__ void predict_kernel(const int* __restrict__ user, const int* __restrict__ item_i,
                               const int* __restrict__ item_j,
                               const float* __restrict__ sum,
                               const float* __restrict__ eu0, const float* __restrict__ ei0,
                               float* __restrict__ out, float* __restrict__ rbuf) {
    __shared__ float rpart[4];
    int t = blockIdx.x * blockDim.x + threadIdx.x;
    int b = t >> 6;
    int d = t & 63;
    int wv = threadIdx.x >> 6;
    float pi = 0.f, pj = 0.f, r = 0.f;
    if (b < BATCH) {
        int u  = user[b];
        int ii = item_i[b];
        int jj = item_j[b];
        float ue = sum[(size_t)u * EMBED + d];
        float ie = sum[((size_t)N_USERS + ii) * EMBED + d];
        float je = sum[((size_t)N_USERS + jj) * EMBED + d];
        pi = ue * ie;
        pj = ue * je;
        float u0 = eu0[(size_t)u  * EMBED + d];
        float i0 = ei0[(size_t)ii * EMBED + d];
        float j0 = ei0[(size_t)jj * EMBED + d];
        r = u0 * u0 + i0 * i0 + j0 * j0;
    }
    #pragma unroll
    for (int off = 32; off > 0; off >>= 1) {
        pi += __shfl_down(pi, off);
        pj += __shfl_down(pj, off);
        r  += __shfl_down(r,  off);
    }
    if (d == 0 && b < BATCH) {
        out[b]         = pi * (1.0f / 16.0f);
        out[BATCH + b] = pj * (1.0f / 16.0f);
        rpart[wv] = r;
    }
    __syncthreads();
    if (threadIdx.x == 0)
        rbuf[blockIdx.x] = rpart[0] + rpart[1] + rpart[2] + rpart[3];
}

// ---------------------------------------------------------------------------
// Reduce the 2048 block partials -> out[2*BATCH]
// ---------------------------------------------------------------------------
__global__ void finalize_reg(const float* __restrict__ rbuf, float* __restrict__ out) {
    __shared__ float lds[4];
    int tid = threadIdx.x;
    float s = 0.f;
    for (int i = tid; i < PRED_BLOCKS; i += 256) s += rbuf[i];
    #pragma unroll
    for (int off = 32; off > 0; off >>= 1) s += __shfl_down(s, off);
    if ((tid & 63) == 0) lds[tid >> 6] = s;
    __syncthreads();
    if (tid == 0)
        out[2 * BATCH] = (lds[0] + lds[1] + lds[2] + lds[3]) * (0.5f / (float)BATCH);
}

// ---------------------------------------------------------------------------
extern "C" void kernel_launch(void* const* d_in, const int* in_sizes, int n_in,
                              void* d_out, int out_size, void* d_ws, size_t ws_size,
                              hipStream_t stream) {
    const int*   user      = (const int*)  d_in[0];
    const int*   item_i    = (const int*)  d_in[1];
    const int*   item_j    = (const int*)  d_in[2];
    const int*   edge_src  = (const int*)  d_in[5];
    const int*   edge_dst  = (const int*)  d_in[6];
    const float* edge_vals = (const float*)d_in[7];
    const float* eu0       = (const float*)d_in[8];
    const float* ei0       = (const float*)d_in[9];
    const int    nnz       = in_sizes[5];

    float* out = (float*)d_out;

    // ---- workspace layout (~97 MB; ebuf aliases Ub+Ib, dead after sort) ----
    float*  sum  = (float*)d_ws;                 // 38.4 MB fp32
    ushort* Ua   = (ushort*)(sum + NE);          // 12.8 MB bf16
    ushort* Ia   = Ua + NU_E;                    //  6.4 MB bf16
    ushort* Ub   = Ia + NI_E;                    // 12.8 MB bf16
    ushort* Ib   = Ub + NU_E;                    //  6.4 MB bf16
    int2*   ep   = (int2*)(Ib + NI_E);           // 19.2 MB sorted {dst,val}
    int*    offs = (int*)(ep + nnz);             // NNODES+1 ints
    int*    Hg   = offs + NNODES + 2;            // NBUCK
    int*    bucket_base  = Hg + NBUCK;           // NBUCK+1
    int*    bucketCursor = bucket_base + NBUCK + 2;
    int*    dhist = bucketCursor + NBUCK + 2;    // DBINS
    int*    dcur  = dhist + DBINS;               // DBINS
    int*    perm  = dcur + DBINS;                // NNODES
    float*  rbuf  = (float*)(perm + NNODES);     // PRED_BLOCKS floats
    int2*   ebuf  = (int2*)Ub;                   // 19.2 MB alias (Ub+Ib)

    // ---- build CSR (ebuf aliases Ub/Ib; both written only by gathers later) ----
    const int tile = (nnz + PBLK - 1) / PBLK;
    hipMemsetAsync(Hg, 0, NBUCK * sizeof(int), stream);
    hipMemsetAsync(dhist, 0, DBINS * sizeof(int), stream);
    hist_bucket<<<PBLK, 1024, 0, stream>>>(edge_src, Hg, nnz, tile);
    scan_bucket<<<1, 1024, 0, stream>>>(Hg, bucket_base, bucketCursor, nnz);
    partition_kernel<<<PBLK, 1024, 0, stream>>>(edge_src, edge_dst, edge_vals,
                                                bucketCursor, ebuf, nnz, tile);
    bucket_sort<<<NBUCK, 1024, 0, stream>>>(bucket_base, ebuf, offs, ep, nnz);

    // ---- degree-sorted permutation ----
    const int nblocksN = (NNODES + 255) / 256;
    deg_hist<<<nblocksN, 256, 0, stream>>>(offs, dhist);
    deg_scan<<<1, DBINS, 0, stream>>>(dhist, dcur);
    deg_scatter<<<nblocksN, 256, 0, stream>>>(offs, dcur, perm);

    // ---- init embeddings (writes Ua/Ia/sum; ebuf region untouched) ----
    const int n4blocks = (int)((NE / 4 + 255) / 256);
    init_emb<<<n4blocks, 256, 0, stream>>>(eu0, ei0, Ua, Ia, sum);

    // ---- 3 merged propagation layers ----
    ushort *Uo = Ua, *Un = Ub, *Io = Ia, *In = Ib;
    const int gwaves  = (NNODES + 7) / 8;                 // 18750
    const int gblocks = (gwaves * 64 + 255) / 256;        // 4688
    for (int l = 0; l < N_LAYERS; ++l) {
        int last = (l == N_LAYERS - 1);
        gather_merged<<<gblocks, 256, 0, stream>>>(offs, ep, perm, Uo, Io,
                                                   Un, In, sum, !last);
        ushort* t1 = Uo; Uo = Un; Un = t1;
        ushort* t2 = Io; Io = In; In = t2;
    }

    // ---- predictions + reg loss ----
    predict_kernel<<<PRED_BLOCKS, 256, 0, stream>>>(
        user, item_i, item_j, sum, eu0, ei0, out, rbuf);
    finalize_reg<<<1, 256, 0, stream>>>(rbuf, out);
}

// Round 7
// 363.914 us; speedup vs baseline: 3.1884x; 3.1884x over previous
//
#include <hip/hip_runtime.h>

#define N_USERS 100000
#define M_ITEMS 50000
#define NNODES  (N_USERS + M_ITEMS)
#define EMBED   64
#define N_LAYERS 3
#define BATCH   8192

#define NU_E ((size_t)N_USERS * EMBED)   // user part, elements
#define NI_E ((size_t)M_ITEMS * EMBED)
#define NE   ((size_t)NNODES * EMBED)    // 9,600,000 elements

#define NPB    256                        // nodes per CSR bucket
#define NBUCK  ((NNODES + NPB - 1) / NPB) // 586
#define PBLK   256                        // partition blocks
#define DBINS  1024                       // degree bins
#define NCH    256                        // degree-sort chunks
#define CHUNK  ((NNODES + NCH - 1) / NCH) // 586
#define HBN    (DBINS * NCH)              // 262144
#define PRED_BLOCKS ((BATCH * 64) / 256)  // 2048

typedef unsigned int uint;

static __device__ __forceinline__ ushort f2bf(float f) {
    uint u = __float_as_uint(f);
    return (ushort)((u + 0x7fffu + ((u >> 16) & 1u)) >> 16);
}
static __device__ __forceinline__ float bf_lo(uint u) { return __uint_as_float(u << 16); }
static __device__ __forceinline__ float bf_hi(uint u) { return __uint_as_float(u & 0xffff0000u); }
static __device__ __forceinline__ float bfs(ushort u) { return __uint_as_float((uint)u << 16); }

// ---------------------------------------------------------------------------
// E0 = bf16(concat(eu0, ei0))
// ---------------------------------------------------------------------------
__global__ void init_emb(const float* __restrict__ eu, const float* __restrict__ ei,
                         ushort* __restrict__ E0) {
    size_t t = (size_t)blockIdx.x * blockDim.x + threadIdx.x;   // ushort4 index
    const size_t nu4 = NU_E / 4;
    const size_t n4  = NE / 4;
    if (t >= n4) return;
    float4 v = (t < nu4) ? ((const float4*)eu)[t] : ((const float4*)ei)[t - nu4];
    ((ushort4*)E0)[t] = make_ushort4(f2bf(v.x), f2bf(v.y), f2bf(v.z), f2bf(v.w));
}

// ---------------------------------------------------------------------------
// CSR K1: per-block LDS histogram of coarse buckets (src>>8) -> global Hg
// ---------------------------------------------------------------------------
__global__ void hist_bucket(const int* __restrict__ src, int* __restrict__ Hg,
                            int nnz, int tile) {
    __shared__ int h[NBUCK];
    for (int i = threadIdx.x; i < NBUCK; i += blockDim.x) h[i] = 0;
    __syncthreads();
    int base = blockIdx.x * tile;
    int end  = min(base + tile, nnz);
    for (int i = base + threadIdx.x; i < end; i += blockDim.x)
        atomicAdd(&h[src[i] >> 8], 1);
    __syncthreads();
    for (int i = threadIdx.x; i < NBUCK; i += blockDim.x)
        if (h[i]) atomicAdd(&Hg[i], h[i]);
}

// ---------------------------------------------------------------------------
// CSR K2: exclusive scan of bucket totals -> bucket_base, bucketCursor
// ---------------------------------------------------------------------------
__global__ void scan_bucket(const int* __restrict__ Hg, int* __restrict__ bucket_base,
                            int* __restrict__ bucketCursor, int nnz) {
    __shared__ int lds[1024];
    int tid = threadIdx.x;
    int v = (tid < NBUCK) ? Hg[tid] : 0;
    lds[tid] = v;
    __syncthreads();
    for (int off = 1; off < 1024; off <<= 1) {
        int t = (tid >= off) ? lds[tid - off] : 0;
        __syncthreads();
        lds[tid] += t;
        __syncthreads();
    }
    if (tid < NBUCK) {
        int ex = (tid > 0) ? lds[tid - 1] : 0;
        bucket_base[tid]  = ex;
        bucketCursor[tid] = ex;
    }
    if (tid == NBUCK) bucket_base[tid] = nnz;
}

// ---------------------------------------------------------------------------
// CSR K3: partition edges into coarse buckets. ebuf.x=(src&255)|(dst_local<<8)
// ---------------------------------------------------------------------------
__global__ void partition_kernel(const int* __restrict__ src, const int* __restrict__ dst,
                                 const float* __restrict__ vals,
                                 int* __restrict__ bucketCursor, int2* __restrict__ ebuf,
                                 int nnz, int tile) {
    __shared__ int h[NBUCK];
    __shared__ int cur[NBUCK];
    for (int i = threadIdx.x; i < NBUCK; i += blockDim.x) h[i] = 0;
    __syncthreads();
    int base = blockIdx.x * tile;
    int end  = min(base + tile, nnz);
    for (int i = base + threadIdx.x; i < end; i += blockDim.x)
        atomicAdd(&h[src[i] >> 8], 1);
    __syncthreads();
    for (int i = threadIdx.x; i < NBUCK; i += blockDim.x)
        cur[i] = h[i] ? atomicAdd(&bucketCursor[i], h[i]) : 0;
    __syncthreads();
    for (int i = base + threadIdx.x; i < end; i += blockDim.x) {
        int s = src[i];
        int d = dst[i];
        float v = vals[i];
        if (d >= N_USERS) d -= N_USERS;          // bipartite-local dst index
        int p = atomicAdd(&cur[s >> 8], 1);
        ebuf[p] = make_int2((s & 255) | (d << 8), __float_as_int(v));
    }
}

// ---------------------------------------------------------------------------
// CSR K4: one block per bucket: LDS counts+scan -> offs[], sort edges -> ep
// ---------------------------------------------------------------------------
__global__ void bucket_sort(const int* __restrict__ bucket_base, const int2* __restrict__ ebuf,
                            int* __restrict__ offs, int2* __restrict__ ep, int nnz) {
    __shared__ int cnt[256];
    __shared__ int sc[256];
    __shared__ int cur[256];
    int b   = blockIdx.x;
    int tid = threadIdx.x;
    int beg = bucket_base[b];
    int end = bucket_base[b + 1];
    if (tid < 256) cnt[tid] = 0;
    __syncthreads();
    for (int i = beg + tid; i < end; i += blockDim.x)
        atomicAdd(&cnt[ebuf[i].x & 255], 1);
    __syncthreads();
    if (tid < 256) sc[tid] = cnt[tid];
    __syncthreads();
    for (int off = 1; off < 256; off <<= 1) {
        int t = (tid >= off && tid < 256) ? sc[tid - off] : 0;
        __syncthreads();
        if (tid < 256) sc[tid] += t;
        __syncthreads();
    }
    if (tid < 256) {
        int nodeBase = beg + ((tid > 0) ? sc[tid - 1] : 0);
        int node = b * NPB + tid;
        if (node < NNODES) offs[node] = nodeBase;
        cur[tid] = nodeBase;
    }
    __syncthreads();
    for (int i = beg + tid; i < end; i += blockDim.x) {
        int2 e = ebuf[i];
        int p = atomicAdd(&cur[e.x & 255], 1);
        ep[p] = make_int2(e.x >> 8, e.y);
    }
    if (b == 0 && tid == 0) offs[NNODES] = nnz;
}

// ---------------------------------------------------------------------------
// Degree sort, contention-free (partition pattern, stable across chunks):
// D1: per-chunk LDS degree hist -> Hb[bin*NCH + chunk]    (no global atomics)
// ---------------------------------------------------------------------------
__global__ void deg_hist_blk(const int* __restrict__ offs, int* __restrict__ Hb) {
    __shared__ int h[DBINS];
    int blk = blockIdx.x;
    for (int i = threadIdx.x; i < DBINS; i += blockDim.x) h[i] = 0;
    __syncthreads();
    int base = blk * CHUNK, end = min(base + CHUNK, NNODES);
    for (int n = base + threadIdx.x; n < end; n += blockDim.x)
        atomicAdd(&h[min(offs[n + 1] - offs[n], DBINS - 1)], 1);
    __syncthreads();
    for (int i = threadIdx.x; i < DBINS; i += blockDim.x)
        Hb[i * NCH + blk] = h[i];
}

// generic 3-phase exclusive scan over n ints (chunked 1024 = 256thr x 4)
__global__ void scan_local(int* __restrict__ h, int* __restrict__ bsum, int n) {
    __shared__ int lds[256];
    const int tid = threadIdx.x;
    const int base = blockIdx.x * 1024 + tid * 4;
    int v[4]; int s = 0;
    #pragma unroll
    for (int c = 0; c < 4; ++c) { v[c] = (base + c < n) ? h[base + c] : 0; s += v[c]; }
    lds[tid] = s;
    __syncthreads();
    for (int off = 1; off < 256; off <<= 1) {
        int t = (tid >= off) ? lds[tid - off] : 0;
        __syncthreads();
        lds[tid] += t;
        __syncthreads();
    }
    if (tid == 255) bsum[blockIdx.x] = lds[255];
    int run = (tid > 0) ? lds[tid - 1] : 0;
    #pragma unroll
    for (int c = 0; c < 4; ++c) {
        int t = v[c];
        if (base + c < n) h[base + c] = run;
        run += t;
    }
}
__global__ void scan_bsums(int* __restrict__ bsum, int nblk) {
    __shared__ int lds[256];
    int tid = threadIdx.x;
    lds[tid] = (tid < nblk) ? bsum[tid] : 0;
    __syncthreads();
    for (int off = 1; off < 256; off <<= 1) {
        int t = (tid >= off) ? lds[tid - off] : 0;
        __syncthreads();
        lds[tid] += t;
        __syncthreads();
    }
    if (tid < nblk) bsum[tid] = (tid > 0) ? lds[tid - 1] : 0;
}
__global__ void scan_add(int* __restrict__ h, const int* __restrict__ bsum, int n) {
    int i = blockIdx.x * blockDim.x + threadIdx.x;
    if (i >= n) return;
    h[i] += bsum[i / 1024];
}

// D3: scatter nodes into perm using scanned Hb bases + LDS cursors only
__global__ void deg_scatter_blk(const int* __restrict__ offs, const int* __restrict__ Hb,
                                int* __restrict__ perm) {
    __shared__ int cur[DBINS];
    int blk = blockIdx.x;
    for (int i = threadIdx.x; i < DBINS; i += blockDim.x)
        cur[i] = Hb[i * NCH + blk];
    __syncthreads();
    int base = blk * CHUNK, end = min(base + CHUNK, NNODES);
    for (int n = base + threadIdx.x; n < end; n += blockDim.x) {
        int d = min(offs[n + 1] - offs[n], DBINS - 1);
        int p = atomicAdd(&cur[d], 1);
        perm[p] = n;
    }
}

// ---------------------------------------------------------------------------
// Gather layer: Enext[node] = sum val * Eprev[other_side(dst)]
// 8 nodes/wave (degree-sorted via perm), 8 lanes/node, branch-free unroll-4:
// inactive slots read row 0 with weight 0.
// ---------------------------------------------------------------------------
__global__ void gather_E(const int* __restrict__ offs, const int2* __restrict__ ep,
                         const int* __restrict__ perm,
                         const ushort* __restrict__ Eprev, ushort* __restrict__ Enext) {
    int t = blockIdx.x * blockDim.x + threadIdx.x;
    int wave = t >> 6;
    int lane = t & 63;
    int g = lane >> 3;              // node slot within wave
    int q = lane & 7;               // uint4 chunk within 128B row
    int ln = wave * 8 + g;
    bool valid = ln < NNODES;
    int node = valid ? perm[ln] : 0;
    int start = valid ? offs[node] : 0;
    int deg   = valid ? offs[node + 1] - start : 0;
    bool isUser = node < N_USERS;
    const uint4* other = (const uint4*)(Eprev + (isUser ? NU_E : 0));

    int md = deg;
    #pragma unroll
    for (int off = 8; off <= 32; off <<= 1) md = max(md, __shfl_xor(md, off));

    float a0=0.f,a1=0.f,a2=0.f,a3=0.f,a4=0.f,a5=0.f,a6=0.f,a7=0.f;
    for (int k = 0; k < md; k += 4) {
        int2 e[4];
        uint4 r[4];
        #pragma unroll
        for (int c = 0; c < 4; ++c)
            e[c] = (k + c < deg) ? ep[start + k + c] : make_int2(0, 0);
        #pragma unroll
        for (int c = 0; c < 4; ++c)
            r[c] = other[(size_t)e[c].x * 8 + q];
        #pragma unroll
        for (int c = 0; c < 4; ++c) {
            float v = __int_as_float(e[c].y);   // 0 for inactive slots
            a0 = fmaf(v, bf_lo(r[c].x), a0);  a1 = fmaf(v, bf_hi(r[c].x), a1);
            a2 = fmaf(v, bf_lo(r[c].y), a2);  a3 = fmaf(v, bf_hi(r[c].y), a3);
            a4 = fmaf(v, bf_lo(r[c].z), a4);  a5 = fmaf(v, bf_hi(r[c].z), a5);
            a6 = fmaf(v, bf_lo(r[c].w), a6);  a7 = fmaf(v, bf_hi(r[c].w), a7);
        }
    }

    if (!valid) return;
    uint4 o;
    o.x = (uint)f2bf(a0) | ((uint)f2bf(a1) << 16);
    o.y = (uint)f2bf(a2) | ((uint)f2bf(a3) << 16);
    o.z = (uint)f2bf(a4) | ((uint)f2bf(a5) << 16);
    o.w = (uint)f2bf(a6) | ((uint)f2bf(a7) << 16);
    ((uint4*)Enext)[(size_t)node * 8 + q] = o;
}

// ---------------------------------------------------------------------------
// Predict: sum 4 generations of bf16 rows, dot, /16; reg-loss block partials.
// ---------------------------------------------------------------------------
__global__ void predict_kernel(const int* __restrict__ user, const int* __restrict__ item_i,
                               const int* __restrict__ item_j,
                               const ushort* __restrict__ E0, const ushort* __restrict__ E1,
                               const ushort* __restrict__ E2, const ushort* __restrict__ E3,
                               const float* __restrict__ eu0, const float* __restrict__ ei0,
                               float* __restrict__ out, float* __restrict__ rbuf) {
    __shared__ float rpart[4];
    int t = blockIdx.x * blockDim.x + threadIdx.x;
    int b = t >> 6;
    int d = t & 63;
    int wv = threadIdx.x >> 6;
    float pi = 0.f, pj = 0.f, r = 0.f;
    if (b < BATCH) {
        size_t ru = (size_t)user[b] * EMBED + d;
        size_t ri = ((size_t)N_USERS + item_i[b]) * EMBED + d;
        size_t rj = ((size_t)N_USERS + item_j[b]) * EMBED + d;
        float ue = bfs(E0[ru]) + bfs(E1[ru]) + bfs(E2[ru]) + bfs(E3[ru]);
        float ie = bfs(E0[ri]) + bfs(E1[ri]) + bfs(E2[ri]) + bfs(E3[ri]);
        float je = bfs(E0[rj]) + bfs(E1[rj]) + bfs(E2[rj]) + bfs(E3[rj]);
        pi = ue * ie;
        pj = ue * je;
        float u0 = eu0[(size_t)user[b] * EMBED + d];
        float i0 = ei0[(size_t)item_i[b] * EMBED + d];
        float j0 = ei0[(size_t)item_j[b] * EMBED + d];
        r = u0 * u0 + i0 * i0 + j0 * j0;
    }
    #pragma unroll
    for (int off = 32; off > 0; off >>= 1) {
        pi += __shfl_down(pi, off);
        pj += __shfl_down(pj, off);
        r  += __shfl_down(r,  off);
    }
    if (d == 0 && b < BATCH) {
        out[b]         = pi * (1.0f / 16.0f);
        out[BATCH + b] = pj * (1.0f / 16.0f);
        rpart[wv] = r;
    }
    __syncthreads();
    if (threadIdx.x == 0)
        rbuf[blockIdx.x] = rpart[0] + rpart[1] + rpart[2] + rpart[3];
}

__global__ void finalize_reg(const float* __restrict__ rbuf, float* __restrict__ out) {
    __shared__ float lds[4];
    int tid = threadIdx.x;
    float s = 0.f;
    for (int i = tid; i < PRED_BLOCKS; i += 256) s += rbuf[i];
    #pragma unroll
    for (int off = 32; off > 0; off >>= 1) s += __shfl_down(s, off);
    if ((tid & 63) == 0) lds[tid >> 6] = s;
    __syncthreads();
    if (tid == 0)
        out[2 * BATCH] = (lds[0] + lds[1] + lds[2] + lds[3]) * (0.5f / (float)BATCH);
}

// ---------------------------------------------------------------------------
extern "C" void kernel_launch(void* const* d_in, const int* in_sizes, int n_in,
                              void* d_out, int out_size, void* d_ws, size_t ws_size,
                              hipStream_t stream) {
    const int*   user      = (const int*)  d_in[0];
    const int*   item_i    = (const int*)  d_in[1];
    const int*   item_j    = (const int*)  d_in[2];
    const int*   edge_src  = (const int*)  d_in[5];
    const int*   edge_dst  = (const int*)  d_in[6];
    const float* edge_vals = (const float*)d_in[7];
    const float* eu0       = (const float*)d_in[8];
    const float* ei0       = (const float*)d_in[9];
    const int    nnz       = in_sizes[5];

    float* out = (float*)d_out;

    // ---- workspace (~99 MB): 4 bf16 generations + CSR + perm scratch ----
    ushort* E0   = (ushort*)d_ws;                // 19.2 MB each
    ushort* E1   = E0 + NE;
    ushort* E2   = E1 + NE;
    ushort* E3   = E2 + NE;
    int2*   ep   = (int2*)(E3 + NE);             // 19.2 MB sorted {dst,val}
    int*    offs = (int*)(ep + nnz);             // NNODES+1
    int*    Hg   = offs + NNODES + 2;            // NBUCK
    int*    bucket_base  = Hg + NBUCK;           // NBUCK+1
    int*    bucketCursor = bucket_base + NBUCK + 2;
    int*    Hb   = bucketCursor + NBUCK + 2;     // DBINS*NCH = 1 MB
    int*    bsum = Hb + HBN;                     // 256
    int*    perm = bsum + 256;                   // NNODES
    float*  rbuf = (float*)(perm + NNODES);      // PRED_BLOCKS
    int2*   ebuf = (int2*)E1;                    // alias: dead before gathers

    // ---- build CSR ----
    const int tile = (nnz + PBLK - 1) / PBLK;
    hipMemsetAsync(Hg, 0, NBUCK * sizeof(int), stream);
    hist_bucket<<<PBLK, 1024, 0, stream>>>(edge_src, Hg, nnz, tile);
    scan_bucket<<<1, 1024, 0, stream>>>(Hg, bucket_base, bucketCursor, nnz);
    partition_kernel<<<PBLK, 1024, 0, stream>>>(edge_src, edge_dst, edge_vals,
                                                bucketCursor, ebuf, nnz, tile);
    bucket_sort<<<NBUCK, 1024, 0, stream>>>(bucket_base, ebuf, offs, ep, nnz);

    // ---- stable degree-sorted permutation (no contended atomics) ----
    deg_hist_blk<<<NCH, 256, 0, stream>>>(offs, Hb);
    scan_local<<<HBN / 1024, 256, 0, stream>>>(Hb, bsum, HBN);
    scan_bsums<<<1, 256, 0, stream>>>(bsum, HBN / 1024);
    scan_add<<<HBN / 256, 256, 0, stream>>>(Hb, bsum, HBN);
    deg_scatter_blk<<<NCH, 256, 0, stream>>>(offs, Hb, perm);

    // ---- init E0 (overwrites nothing needed; ebuf=E1 already consumed) ----
    init_emb<<<(int)((NE / 4 + 255) / 256), 256, 0, stream>>>(eu0, ei0, E0);

    // ---- 3 merged propagation layers (pure gather, no sum RMW) ----
    const int gblocks = (int)((((NNODES + 7) / 8) * 64 + 255) / 256);
    gather_E<<<gblocks, 256, 0, stream>>>(offs, ep, perm, E0, E1);
    gather_E<<<gblocks, 256, 0, stream>>>(offs, ep, perm, E1, E2);
    gather_E<<<gblocks, 256, 0, stream>>>(offs, ep, perm, E2, E3);

    // ---- predictions + reg loss ----
    predict_kernel<<<PRED_BLOCKS, 256, 0, stream>>>(
        user, item_i, item_j, E0, E1, E2, E3, eu0, ei0, out, rbuf);
    finalize_reg<<<1, 256, 0, stream>>>(rbuf, out);
}

// Round 8
// 336.274 us; speedup vs baseline: 3.4505x; 1.0822x over previous
//
#include <hip/hip_runtime.h>

#define N_USERS 100000
#define M_ITEMS 50000
#define NNODES  (N_USERS + M_ITEMS)
#define EMBED   64
#define N_LAYERS 3
#define BATCH   8192

#define NU_E ((size_t)N_USERS * EMBED)
#define NI_E ((size_t)M_ITEMS * EMBED)
#define NE   ((size_t)NNODES * EMBED)    // 9,600,000 elements

#define NPB    256                        // nodes per CSR bucket
#define NBUCK  ((NNODES + NPB - 1) / NPB) // 586
#define PBLK   256                        // partition blocks
#define HBB_N  (NBUCK * PBLK)             // 150,016 (bucket-major count matrix)
#define DBINS  1024                       // degree bins
#define NCH    256                        // degree-sort chunks
#define CHUNK  ((NNODES + NCH - 1) / NCH) // 586
#define HBN    (DBINS * NCH)              // 262,144
#define PRED_BLOCKS ((BATCH * 64) / 256)  // 2048

typedef unsigned int uint;

static __device__ __forceinline__ ushort f2bf(float f) {
    uint u = __float_as_uint(f);
    return (ushort)((u + 0x7fffu + ((u >> 16) & 1u)) >> 16);
}
static __device__ __forceinline__ float bf_lo(uint u) { return __uint_as_float(u << 16); }
static __device__ __forceinline__ float bf_hi(uint u) { return __uint_as_float(u & 0xffff0000u); }
static __device__ __forceinline__ float bfs(ushort u) { return __uint_as_float((uint)u << 16); }

// ---------------------------------------------------------------------------
// E0 = bf16(concat(eu0, ei0))
// ---------------------------------------------------------------------------
__global__ void init_emb(const float* __restrict__ eu, const float* __restrict__ ei,
                         ushort* __restrict__ E0) {
    size_t t = (size_t)blockIdx.x * blockDim.x + threadIdx.x;   // ushort4 index
    const size_t nu4 = NU_E / 4;
    const size_t n4  = NE / 4;
    if (t >= n4) return;
    float4 v = (t < nu4) ? ((const float4*)eu)[t] : ((const float4*)ei)[t - nu4];
    ((ushort4*)E0)[t] = make_ushort4(f2bf(v.x), f2bf(v.y), f2bf(v.z), f2bf(v.w));
}

// ---------------------------------------------------------------------------
// CSR pass 1: per-block bucket histogram -> Hbb[bucket*PBLK + block]
// (bucket-major so a single exclusive scan yields stable per-block cursors)
// ---------------------------------------------------------------------------
__global__ void hist_pass(const int* __restrict__ src, int* __restrict__ Hbb,
                          int nnz, int tile) {
    __shared__ int h[NBUCK];
    for (int i = threadIdx.x; i < NBUCK; i += blockDim.x) h[i] = 0;
    __syncthreads();
    int base = blockIdx.x * tile;
    int end  = min(base + tile, nnz);
    for (int i = base + threadIdx.x; i < end; i += blockDim.x)
        atomicAdd(&h[src[i] >> 8], 1);
    __syncthreads();
    for (int i = threadIdx.x; i < NBUCK; i += blockDim.x)
        Hbb[i * PBLK + blockIdx.x] = h[i];
}

// ---------------------------------------------------------------------------
// Generic 3-phase exclusive scan (1024 elems per block = 256 thr x 4)
// ---------------------------------------------------------------------------
__global__ void scan_local(int* __restrict__ h, int* __restrict__ bsum, int n) {
    __shared__ int lds[256];
    const int tid = threadIdx.x;
    const int base = blockIdx.x * 1024 + tid * 4;
    int v[4]; int s = 0;
    #pragma unroll
    for (int c = 0; c < 4; ++c) { v[c] = (base + c < n) ? h[base + c] : 0; s += v[c]; }
    lds[tid] = s;
    __syncthreads();
    for (int off = 1; off < 256; off <<= 1) {
        int t = (tid >= off) ? lds[tid - off] : 0;
        __syncthreads();
        lds[tid] += t;
        __syncthreads();
    }
    if (tid == 255) bsum[blockIdx.x] = lds[255];
    int run = (tid > 0) ? lds[tid - 1] : 0;
    #pragma unroll
    for (int c = 0; c < 4; ++c) {
        int t = v[c];
        if (base + c < n) h[base + c] = run;
        run += t;
    }
}
__global__ void scan_bsums(int* __restrict__ bsum, int nblk) {
    __shared__ int lds[256];
    int tid = threadIdx.x;
    lds[tid] = (tid < nblk) ? bsum[tid] : 0;
    __syncthreads();
    for (int off = 1; off < 256; off <<= 1) {
        int t = (tid >= off) ? lds[tid - off] : 0;
        __syncthreads();
        lds[tid] += t;
        __syncthreads();
    }
    if (tid < nblk) bsum[tid] = (tid > 0) ? lds[tid - 1] : 0;
}
__global__ void scan_add(int* __restrict__ h, const int* __restrict__ bsum, int n) {
    int i = blockIdx.x * blockDim.x + threadIdx.x;
    if (i >= n) return;
    h[i] += bsum[i / 1024];
}

// ---------------------------------------------------------------------------
// CSR pass 2: stable partition into bucket runs using scanned Hbb cursors.
// ebuf.x = (src & 255) | (dst_local << 8)
// ---------------------------------------------------------------------------
__global__ void partition2(const int* __restrict__ src, const int* __restrict__ dst,
                           const float* __restrict__ vals, const int* __restrict__ Hbb,
                           int2* __restrict__ ebuf, int nnz, int tile) {
    __shared__ int cur[NBUCK];
    for (int i = threadIdx.x; i < NBUCK; i += blockDim.x)
        cur[i] = Hbb[i * PBLK + blockIdx.x];
    __syncthreads();
    int base = blockIdx.x * tile;
    int end  = min(base + tile, nnz);
    for (int i = base + threadIdx.x; i < end; i += blockDim.x) {
        int s = src[i];
        int d = dst[i];
        float v = vals[i];
        if (d >= N_USERS) d -= N_USERS;          // bipartite-local dst index
        int p = atomicAdd(&cur[s >> 8], 1);
        ebuf[p] = make_int2((s & 255) | (d << 8), __float_as_int(v));
    }
}

// ---------------------------------------------------------------------------
// CSR pass 3: one block per bucket: LDS counts+scan -> offs[], sort -> ep
// bucket range comes from scanned Hbb: beg = Hbb[b*PBLK], end = Hbb[(b+1)*PBLK]
// ---------------------------------------------------------------------------
__global__ void bucket_sort(const int* __restrict__ Hbb, const int2* __restrict__ ebuf,
                            int* __restrict__ offs, int2* __restrict__ ep, int nnz) {
    __shared__ int cnt[256];
    __shared__ int sc[256];
    __shared__ int cur[256];
    int b   = blockIdx.x;
    int tid = threadIdx.x;
    int beg = Hbb[b * PBLK];
    int end = (b + 1 < NBUCK) ? Hbb[(b + 1) * PBLK] : nnz;
    if (tid < 256) cnt[tid] = 0;
    __syncthreads();
    for (int i = beg + tid; i < end; i += blockDim.x)
        atomicAdd(&cnt[ebuf[i].x & 255], 1);
    __syncthreads();
    if (tid < 256) sc[tid] = cnt[tid];
    __syncthreads();
    for (int off = 1; off < 256; off <<= 1) {
        int t = (tid >= off && tid < 256) ? sc[tid - off] : 0;
        __syncthreads();
        if (tid < 256) sc[tid] += t;
        __syncthreads();
    }
    if (tid < 256) {
        int nodeBase = beg + ((tid > 0) ? sc[tid - 1] : 0);
        int node = b * NPB + tid;
        if (node < NNODES) offs[node] = nodeBase;
        cur[tid] = nodeBase;
    }
    __syncthreads();
    for (int i = beg + tid; i < end; i += blockDim.x) {
        int2 e = ebuf[i];
        int p = atomicAdd(&cur[e.x & 255], 1);
        ep[p] = make_int2(e.x >> 8, e.y);
    }
    if (b == 0 && tid == 0) offs[NNODES] = nnz;
}

// ---------------------------------------------------------------------------
// Degree sort (contention-free, stable): per-chunk LDS hist -> Hb -> scan ->
// scatter with LDS cursors.
// ---------------------------------------------------------------------------
__global__ void deg_hist_blk(const int* __restrict__ offs, int* __restrict__ Hb) {
    __shared__ int h[DBINS];
    int blk = blockIdx.x;
    for (int i = threadIdx.x; i < DBINS; i += blockDim.x) h[i] = 0;
    __syncthreads();
    int base = blk * CHUNK, end = min(base + CHUNK, NNODES);
    for (int n = base + threadIdx.x; n < end; n += blockDim.x)
        atomicAdd(&h[min(offs[n + 1] - offs[n], DBINS - 1)], 1);
    __syncthreads();
    for (int i = threadIdx.x; i < DBINS; i += blockDim.x)
        Hb[i * NCH + blk] = h[i];
}
__global__ void deg_scatter_blk(const int* __restrict__ offs, const int* __restrict__ Hb,
                                int* __restrict__ perm) {
    __shared__ int cur[DBINS];
    int blk = blockIdx.x;
    for (int i = threadIdx.x; i < DBINS; i += blockDim.x)
        cur[i] = Hb[i * NCH + blk];
    __syncthreads();
    int base = blk * CHUNK, end = min(base + CHUNK, NNODES);
    for (int n = base + threadIdx.x; n < end; n += blockDim.x) {
        int d = min(offs[n + 1] - offs[n], DBINS - 1);
        int p = atomicAdd(&cur[d], 1);
        perm[p] = n;
    }
}

// ---------------------------------------------------------------------------
// Gather layer: Enext[node] = sum val * Eprev[other_side(dst)]
// 8 nodes/wave (degree-sorted), 8 lanes/node, branch-free unroll-8.
// Inactive slots clamp to the node's last valid edge (L1/L2-hit) with weight 0.
// ---------------------------------------------------------------------------
__global__ void gather_E(const int* __restrict__ offs, const int2* __restrict__ ep,
                         const int* __restrict__ perm,
                         const ushort* __restrict__ Eprev, ushort* __restrict__ Enext,
                         int nnz) {
    int t = blockIdx.x * blockDim.x + threadIdx.x;
    int wave = t >> 6;
    int lane = t & 63;
    int g = lane >> 3;              // node slot within wave
    int q = lane & 7;               // uint4 chunk within 128B row
    int ln = wave * 8 + g;
    bool valid = ln < NNODES;
    int node = valid ? perm[ln] : 0;
    int start = valid ? offs[node] : 0;
    int deg   = valid ? offs[node + 1] - start : 0;
    bool isUser = node < N_USERS;
    const uint4* other = (const uint4*)(Eprev + (isUser ? NU_E : 0));
    int lastIdx = min(max(start + deg - 1, 0), nnz - 1);   // clamp target

    int md = deg;
    #pragma unroll
    for (int off = 8; off <= 32; off <<= 1) md = max(md, __shfl_xor(md, off));

    float a0=0.f,a1=0.f,a2=0.f,a3=0.f,a4=0.f,a5=0.f,a6=0.f,a7=0.f;
    for (int k = 0; k < md; k += 8) {
        int2 e[8];
        uint4 r[8];
        #pragma unroll
        for (int c = 0; c < 8; ++c) {
            int idx = (k + c < deg) ? start + k + c : lastIdx;
            e[c] = ep[idx];
            if (k + c >= deg) e[c].y = 0;     // weight 0 on padded slots
        }
        #pragma unroll
        for (int c = 0; c < 8; ++c)
            r[c] = other[(size_t)e[c].x * 8 + q];
        #pragma unroll
        for (int c = 0; c < 8; ++c) {
            float v = __int_as_float(e[c].y);
            a0 = fmaf(v, bf_lo(r[c].x), a0);  a1 = fmaf(v, bf_hi(r[c].x), a1);
            a2 = fmaf(v, bf_lo(r[c].y), a2);  a3 = fmaf(v, bf_hi(r[c].y), a3);
            a4 = fmaf(v, bf_lo(r[c].z), a4);  a5 = fmaf(v, bf_hi(r[c].z), a5);
            a6 = fmaf(v, bf_lo(r[c].w), a6);  a7 = fmaf(v, bf_hi(r[c].w), a7);
        }
    }

    if (!valid) return;
    uint4 o;
    o.x = (uint)f2bf(a0) | ((uint)f2bf(a1) << 16);
    o.y = (uint)f2bf(a2) | ((uint)f2bf(a3) << 16);
    o.z = (uint)f2bf(a4) | ((uint)f2bf(a5) << 16);
    o.w = (uint)f2bf(a6) | ((uint)f2bf(a7) << 16);
    ((uint4*)Enext)[(size_t)node * 8 + q] = o;
}

// ---------------------------------------------------------------------------
// Predict: sum 4 generations of bf16 rows, dot, /16; reg-loss block partials.
// ---------------------------------------------------------------------------
__global__ void predict_kernel(const int* __restrict__ user, const int* __restrict__ item_i,
                               const int* __restrict__ item_j,
                               const ushort* __restrict__ E0, const ushort* __restrict__ E1,
                               const ushort* __restrict__ E2, const ushort* __restrict__ E3,
                               const float* __restrict__ eu0, const float* __restrict__ ei0,
                               float* __restrict__ out, float* __restrict__ rbuf) {
    __shared__ float rpart[4];
    int t = blockIdx.x * blockDim.x + threadIdx.x;
    int b = t >> 6;
    int d = t & 63;
    int wv = threadIdx.x >> 6;
    float pi = 0.f, pj = 0.f, r = 0.f;
    if (b < BATCH) {
        size_t ru = (size_t)user[b] * EMBED + d;
        size_t ri = ((size_t)N_USERS + item_i[b]) * EMBED + d;
        size_t rj = ((size_t)N_USERS + item_j[b]) * EMBED + d;
        float ue = bfs(E0[ru]) + bfs(E1[ru]) + bfs(E2[ru]) + bfs(E3[ru]);
        float ie = bfs(E0[ri]) + bfs(E1[ri]) + bfs(E2[ri]) + bfs(E3[ri]);
        float je = bfs(E0[rj]) + bfs(E1[rj]) + bfs(E2[rj]) + bfs(E3[rj]);
        pi = ue * ie;
        pj = ue * je;
        float u0 = eu0[(size_t)user[b] * EMBED + d];
        float i0 = ei0[(size_t)item_i[b] * EMBED + d];
        float j0 = ei0[(size_t)item_j[b] * EMBED + d];
        r = u0 * u0 + i0 * i0 + j0 * j0;
    }
    #pragma unroll
    for (int off = 32; off > 0; off >>= 1) {
        pi += __shfl_down(pi, off);
        pj += __shfl_down(pj, off);
        r  += __shfl_down(r,  off);
    }
    if (d == 0 && b < BATCH) {
        out[b]         = pi * (1.0f / 16.0f);
        out[BATCH + b] = pj * (1.0f / 16.0f);
        rpart[wv] = r;
    }
    __syncthreads();
    if (threadIdx.x == 0)
        rbuf[blockIdx.x] = rpart[0] + rpart[1] + rpart[2] + rpart[3];
}

__global__ void finalize_reg(const float* __restrict__ rbuf, float* __restrict__ out) {
    __shared__ float lds[4];
    int tid = threadIdx.x;
    float s = 0.f;
    for (int i = tid; i < PRED_BLOCKS; i += 256) s += rbuf[i];
    #pragma unroll
    for (int off = 32; off > 0; off >>= 1) s += __shfl_down(s, off);
    if ((tid & 63) == 0) lds[tid >> 6] = s;
    __syncthreads();
    if (tid == 0)
        out[2 * BATCH] = (lds[0] + lds[1] + lds[2] + lds[3]) * (0.5f / (float)BATCH);
}

// ---------------------------------------------------------------------------
extern "C" void kernel_launch(void* const* d_in, const int* in_sizes, int n_in,
                              void* d_out, int out_size, void* d_ws, size_t ws_size,
                              hipStream_t stream) {
    const int*   user      = (const int*)  d_in[0];
    const int*   item_i    = (const int*)  d_in[1];
    const int*   item_j    = (const int*)  d_in[2];
    const int*   edge_src  = (const int*)  d_in[5];
    const int*   edge_dst  = (const int*)  d_in[6];
    const float* edge_vals = (const float*)d_in[7];
    const float* eu0       = (const float*)d_in[8];
    const float* ei0       = (const float*)d_in[9];
    const int    nnz       = in_sizes[5];

    float* out = (float*)d_out;

    // ---- workspace (~100 MB) ----
    ushort* E0   = (ushort*)d_ws;                // 19.2 MB each
    ushort* E1   = E0 + NE;
    ushort* E2   = E1 + NE;
    ushort* E3   = E2 + NE;
    int2*   ep   = (int2*)(E3 + NE);             // 19.2 MB sorted {dst,val}
    int*    offs = (int*)(ep + nnz);             // NNODES+1
    int*    Hbb  = offs + NNODES + 2;            // NBUCK*PBLK = 150,016
    int*    bs1  = Hbb + HBB_N;                  // 256 (scan bsums for Hbb)
    int*    Hb   = bs1 + 256;                    // DBINS*NCH = 262,144
    int*    bs2  = Hb + HBN;                     // 256
    int*    perm = bs2 + 256;                    // NNODES
    float*  rbuf = (float*)(perm + NNODES);      // PRED_BLOCKS
    int2*   ebuf = (int2*)E1;                    // alias: dead before gathers

    // ---- CSR build: stable 2-pass radix (no global atomics) ----
    const int tile = (nnz + PBLK - 1) / PBLK;
    const int nblk1 = (HBB_N + 1023) / 1024;     // 147
    hist_pass<<<PBLK, 1024, 0, stream>>>(edge_src, Hbb, nnz, tile);
    scan_local<<<nblk1, 256, 0, stream>>>(Hbb, bs1, HBB_N);
    scan_bsums<<<1, 256, 0, stream>>>(bs1, nblk1);
    scan_add<<<(HBB_N + 1023) / 1024, 1024, 0, stream>>>(Hbb, bs1, HBB_N);
    partition2<<<PBLK, 1024, 0, stream>>>(edge_src, edge_dst, edge_vals,
                                          Hbb, ebuf, nnz, tile);
    bucket_sort<<<NBUCK, 1024, 0, stream>>>(Hbb, ebuf, offs, ep, nnz);

    // ---- stable degree-sorted permutation ----
    deg_hist_blk<<<NCH, 256, 0, stream>>>(offs, Hb);
    scan_local<<<HBN / 1024, 256, 0, stream>>>(Hb, bs2, HBN);
    scan_bsums<<<1, 256, 0, stream>>>(bs2, HBN / 1024);
    scan_add<<<HBN / 1024, 1024, 0, stream>>>(Hb, bs2, HBN);
    deg_scatter_blk<<<NCH, 256, 0, stream>>>(offs, Hb, perm);

    // ---- init E0 ----
    init_emb<<<(int)((NE / 4 + 255) / 256), 256, 0, stream>>>(eu0, ei0, E0);

    // ---- 3 propagation layers (pure gather) ----
    const int gblocks = (int)((((NNODES + 7) / 8) * 64 + 255) / 256);
    gather_E<<<gblocks, 256, 0, stream>>>(offs, ep, perm, E0, E1, nnz);
    gather_E<<<gblocks, 256, 0, stream>>>(offs, ep, perm, E1, E2, nnz);
    gather_E<<<gblocks, 256, 0, stream>>>(offs, ep, perm, E2, E3, nnz);

    // ---- predictions + reg loss ----
    predict_kernel<<<PRED_BLOCKS, 256, 0, stream>>>(
        user, item_i, item_j, E0, E1, E2, E3, eu0, ei0, out, rbuf);
    finalize_reg<<<1, 256, 0, stream>>>(rbuf, out);
}